// Round 1
// 882.371 us; speedup vs baseline: 1.1772x; 1.1772x over previous
//
#include <hip/hip_runtime.h>

#define B 32
#define N 4096
#define C 768
#define H 12
#define D 64
#define SCALE 0.125f
#define CH 16      // chunks per batch row
#define NT 256     // tokens per chunk
#define TILE 8     // tokens per tile
#define NTILE 32   // NT/TILE

typedef __attribute__((ext_vector_type(4))) float f4;

// K1: q[b][j] = sum_c x[b,0,c] * Wq[c,j]   grid (B,3), coalesced Wq reads
__global__ __launch_bounds__(256)
void k_q(const float* __restrict__ x, const float* __restrict__ Wq,
         float* __restrict__ q){
  int b = blockIdx.x, jb = blockIdx.y, tid = threadIdx.x;
  __shared__ float xs[C];
  for (int c = tid; c < C; c += 256) xs[c] = x[(size_t)b*N*C + c];
  __syncthreads();
  int j = jb*256 + tid;
  float acc = 0.f;
  #pragma unroll 8
  for (int c = 0; c < C; ++c) acc += xs[c] * Wq[(size_t)c*C + j];
  q[(size_t)b*C + j] = acc;
}

// K2: r[b][h][c] = SCALE * sum_d q[b,h*64+d] * Wkv[c, h*64+d]
// grid (B,H); wave-per-row, coalesced Wkv reads, shuffle reduce over d.
__global__ __launch_bounds__(256)
void k_r(const float* __restrict__ q, const float* __restrict__ Wkv,
         float* __restrict__ r){
  int b = blockIdx.x, h = blockIdx.y;
  int tid = threadIdx.x, w = tid >> 6, lane = tid & 63;
  float qv = q[(size_t)b*C + h*D + lane] * SCALE;
  for (int c = w; c < C; c += 4){
    float wv = Wkv[(size_t)c*(2*C) + h*D + lane];
    float p = qv * wv;
    #pragma unroll
    for (int m = 1; m < 64; m <<= 1) p += __shfl_xor(p, m, 64);
    if (lane == 0) r[((size_t)b*H + h)*C + c] = p;
  }
}

// K3 (fused): per (b, chunk): scores -> online softmax -> unnormalized xbar.
// One pass over x. Partials: pm/pl [B][CH][H], pxb [B][CH][H][C].
__global__ __launch_bounds__(256)
void k_fused(const float* __restrict__ x, const float* __restrict__ r,
             float* __restrict__ pm, float* __restrict__ pl,
             float* __restrict__ pxb){
  int b = blockIdx.x, ch = blockIdx.y;
  int tid = threadIdx.x, w = tid >> 6, lane = tid & 63;

  __shared__ float xs[TILE][C];       // 24576 B token tile
  __shared__ float scr[TILE][H][20];  // 7680 B  16-lane score partials (padded)
  __shared__ float sc[TILE][16];      // tile scores
  __shared__ float wts[TILE][16];     // tile softmax weights
  __shared__ float als[16];           // per-head rescale factor

  // per-wave r rows (heads 3w..3w+2) held in registers, loaded once (coalesced)
  f4 rr4[3][3];
  {
    const float* rb = r + ((size_t)b*H + 3*w)*C + 4*lane;
    #pragma unroll
    for (int hh = 0; hh < 3; ++hh)
      #pragma unroll
      for (int jj = 0; jj < 3; ++jj)
        rr4[hh][jj] = *(const f4*)(rb + hh*C + 256*jj);
  }

  float m0 = -1e30f, l0 = 0.f;   // live in threads 0..11 only
  float xb[H][3];
  #pragma unroll
  for (int h = 0; h < H; ++h){ xb[h][0]=0.f; xb[h][1]=0.f; xb[h][2]=0.f; }

  const float* gx = x + ((size_t)b*N + (size_t)ch*NT)*C;
  f4 pf[6];
  #pragma unroll
  for (int k = 0; k < 6; ++k) pf[k] = ((const f4*)gx)[tid + 256*k];

  for (int tt = 0; tt < NTILE; ++tt){
    // stage prefetched tile, issue prefetch for next tile (hides HBM latency)
    f4* xd = (f4*)&xs[0][0];
    #pragma unroll
    for (int k = 0; k < 6; ++k) xd[tid + 256*k] = pf[k];
    if (tt + 1 < NTILE){
      const f4* gn = (const f4*)(gx + (size_t)(tt+1)*TILE*C);
      #pragma unroll
      for (int k = 0; k < 6; ++k) pf[k] = gn[tid + 256*k];
    }
    __syncthreads();                       // (1) xs ready

    // ---- scores: wave w computes heads 3w..3w+2 for all 8 tokens
    float acc[TILE][3];
    #pragma unroll
    for (int t = 0; t < TILE; ++t){ acc[t][0]=0.f; acc[t][1]=0.f; acc[t][2]=0.f; }
    #pragma unroll
    for (int t = 0; t < TILE; ++t){
      f4 p0 = *(const f4*)&xs[t][4*lane];
      f4 p1 = *(const f4*)&xs[t][4*lane + 256];
      f4 p2 = *(const f4*)&xs[t][4*lane + 512];
      #pragma unroll
      for (int hh = 0; hh < 3; ++hh){
        f4 r0 = rr4[hh][0], r1 = rr4[hh][1], r2 = rr4[hh][2];
        acc[t][hh] += p0.x*r0.x + p0.y*r0.y + p0.z*r0.z + p0.w*r0.w
                    + p1.x*r1.x + p1.y*r1.y + p1.z*r1.z + p1.w*r1.w
                    + p2.x*r2.x + p2.y*r2.y + p2.z*r2.z + p2.w*r2.w;
      }
    }
    // 2-stage butterfly: 64 -> 16 partials per (t,h)
    #pragma unroll
    for (int t = 0; t < TILE; ++t)
      #pragma unroll
      for (int hh = 0; hh < 3; ++hh){
        acc[t][hh] += __shfl_xor(acc[t][hh], 32, 64);
        acc[t][hh] += __shfl_xor(acc[t][hh], 16, 64);
      }
    if (lane < 16){
      #pragma unroll
      for (int t = 0; t < TILE; ++t)
        #pragma unroll
        for (int hh = 0; hh < 3; ++hh)
          scr[t][3*w + hh][lane] = acc[t][hh];
    }
    __syncthreads();                       // (2) scr ready

    // ---- final reduce 16 -> 1: 96 threads, one (t,h) each
    if (tid < 96){
      int t8 = tid & 7, h12 = tid >> 3;
      float s = 0.f;
      #pragma unroll
      for (int qq = 0; qq < 4; ++qq){
        f4 v = *(const f4*)&scr[t8][h12][4*qq];
        s += v.x + v.y + v.z + v.w;
      }
      sc[t8][h12] = s;
    }
    __syncthreads();                       // (3) sc ready

    // ---- online-softmax state update (threads 0..11, one head each)
    if (tid < H){
      float tm = sc[0][tid];
      #pragma unroll
      for (int t = 1; t < TILE; ++t) tm = fmaxf(tm, sc[t][tid]);
      float mnew = fmaxf(m0, tm);
      float alpha = __expf(m0 - mnew);
      float wsum = 0.f;
      #pragma unroll
      for (int t = 0; t < TILE; ++t){
        float wv = __expf(sc[t][tid] - mnew);
        wts[t][tid] = wv;
        wsum += wv;
      }
      l0 = l0*alpha + wsum;
      m0 = mnew;
      als[tid] = alpha;
    }
    __syncthreads();                       // (4) wts/als ready

    // ---- xbar accumulate: thread owns c = {tid, tid+256, tid+512}, all heads
    f4 av0 = *(const f4*)&als[0];
    f4 av1 = *(const f4*)&als[4];
    f4 av2 = *(const f4*)&als[8];
    float alf[H] = {av0.x,av0.y,av0.z,av0.w, av1.x,av1.y,av1.z,av1.w,
                    av2.x,av2.y,av2.z,av2.w};
    #pragma unroll
    for (int h = 0; h < H; ++h){
      xb[h][0] *= alf[h]; xb[h][1] *= alf[h]; xb[h][2] *= alf[h];
    }
    #pragma unroll
    for (int t = 0; t < TILE; ++t){
      f4 w0 = *(const f4*)&wts[t][0];
      f4 w1 = *(const f4*)&wts[t][4];
      f4 w2 = *(const f4*)&wts[t][8];
      float wf[H] = {w0.x,w0.y,w0.z,w0.w, w1.x,w1.y,w1.z,w1.w,
                     w2.x,w2.y,w2.z,w2.w};
      float x0 = xs[t][tid], x1 = xs[t][tid+256], x2 = xs[t][tid+512];
      #pragma unroll
      for (int h = 0; h < H; ++h){
        xb[h][0] += wf[h]*x0;
        xb[h][1] += wf[h]*x1;
        xb[h][2] += wf[h]*x2;
      }
    }
    __syncthreads();                       // (5) xs/wts free for next tile
  }

  // write partials
  size_t pbase = ((size_t)b*CH + ch)*H;
  if (tid < H){ pm[pbase + tid] = m0; pl[pbase + tid] = l0; }
  #pragma unroll
  for (int h = 0; h < H; ++h){
    size_t o = (pbase + h)*C + tid;
    pxb[o]       = xb[h][0];
    pxb[o + 256] = xb[h][1];
    pxb[o + 512] = xb[h][2];
  }
}

// K4: merge partials -> xbar[b,h,:], then cls[b][h*64+d] = sum_c xbar * WkvV
__global__ __launch_bounds__(256)
void k_cls(const float* __restrict__ pm, const float* __restrict__ pl,
           const float* __restrict__ pxb, const float* __restrict__ Wkv,
           float* __restrict__ cls){
  int b = blockIdx.x, h = blockIdx.y, tid = threadIdx.x;
  __shared__ float xsm[C];
  float M = -1e30f;
  #pragma unroll
  for (int c = 0; c < CH; ++c) M = fmaxf(M, pm[((size_t)b*CH + c)*H + h]);
  float L = 0.f;
  float eh[CH];
  #pragma unroll
  for (int c = 0; c < CH; ++c){
    eh[c] = __expf(pm[((size_t)b*CH + c)*H + h] - M);
    L += pl[((size_t)b*CH + c)*H + h]*eh[c];
  }
  float inv = 1.f/L;
  #pragma unroll
  for (int k = 0; k < 3; ++k){
    int c = tid + 256*k;
    float acc = 0.f;
    #pragma unroll
    for (int q = 0; q < CH; ++q)
      acc += eh[q]*pxb[(((size_t)b*CH + q)*H + h)*C + c];
    xsm[c] = acc*inv;
  }
  __syncthreads();
  int d = tid & 63, part = tid >> 6;
  float acc = 0.f;
  int c0 = part*192;
  #pragma unroll 4
  for (int cc = c0; cc < c0 + 192; ++cc)
    acc += xsm[cc]*Wkv[(size_t)cc*(2*C) + C + h*D + d];
  __shared__ float red[4][D];
  red[part][d] = acc; __syncthreads();
  if (tid < D)
    cls[(size_t)b*C + h*D + tid] = red[0][tid]+red[1][tid]+red[2][tid]+red[3][tid];
}

// K5: out[b][j] = bp[j] + sum_i cls[b][i] * Wp[i][j]
__global__ __launch_bounds__(256)
void k_out(const float* __restrict__ cls, const float* __restrict__ Wp,
           const float* __restrict__ bp, float* __restrict__ out){
  int b = blockIdx.x, jb = blockIdx.y, tid = threadIdx.x;
  __shared__ float xs[C];
  for (int i = tid; i < C; i += 256) xs[i] = cls[(size_t)b*C + i];
  __syncthreads();
  int j = jb*256 + tid;
  float acc = bp[j];
  #pragma unroll 4
  for (int i = 0; i < C; ++i) acc += xs[i]*Wp[(size_t)i*C + j];
  out[(size_t)b*C + j] = acc;
}

extern "C" void kernel_launch(void* const* d_in, const int* in_sizes, int n_in,
                              void* d_out, int out_size, void* d_ws, size_t ws_size,
                              hipStream_t stream){
  const float* x   = (const float*)d_in[0];
  const float* Wq  = (const float*)d_in[1];
  const float* Wkv = (const float*)d_in[2];
  const float* Wp  = (const float*)d_in[3];
  const float* bp  = (const float*)d_in[4];
  float* out = (float*)d_out;
  char* ws = (char*)d_ws;
  float* q   = (float*)(ws + 0);          //    98,304 B
  float* r   = (float*)(ws + 98304);      // 1,179,648 B
  float* pm  = (float*)(ws + 1277952);    //    24,576 B
  float* pl  = (float*)(ws + 1302528);    //    24,576 B
  float* pxb = (float*)(ws + 1327104);    // 18,874,368 B
  float* cls = (float*)(ws + 20201472);   //    98,304 B  (total 20,299,776 B)

  k_q    <<<dim3(B,3),  dim3(256), 0, stream>>>(x, Wq, q);
  k_r    <<<dim3(B,H),  dim3(256), 0, stream>>>(q, Wkv, r);
  k_fused<<<dim3(B,CH), dim3(256), 0, stream>>>(x, r, pm, pl, pxb);
  k_cls  <<<dim3(B,H),  dim3(256), 0, stream>>>(pm, pl, pxb, Wkv, cls);
  k_out  <<<dim3(B,3),  dim3(256), 0, stream>>>(cls, Wp, bp, out);
}

// Round 3
// 854.201 us; speedup vs baseline: 1.2160x; 1.0330x over previous
//
#include <hip/hip_runtime.h>

#define B 32
#define N 4096
#define C 768
#define H 12
#define D 64
#define SCALE 0.125f
#define CH 32      // chunks per batch row
#define NT 128     // tokens per chunk
#define TILE 8     // tokens per tile
#define NTILE 16   // NT/TILE

typedef __attribute__((ext_vector_type(4))) float f4;

// K1 (fused q+r): per (b,h): q_h[d] = sum_c x[b,0,c]*Wq[c,h*64+d], scaled;
// then r[b,h,c] = sum_d q_h[d]*Wkv[c, h*64+d].
__global__ __launch_bounds__(256)
void k_qr(const float* __restrict__ x, const float* __restrict__ Wq,
          const float* __restrict__ Wkv, float* __restrict__ r){
  int b = blockIdx.x, h = blockIdx.y;
  int tid = threadIdx.x, w = tid >> 6, lane = tid & 63;
  __shared__ float xs[C];
  __shared__ float qred[4][D];
  __shared__ float qs[D];
  for (int c = tid; c < C; c += 256) xs[c] = x[(size_t)b*N*C + c];
  __syncthreads();
  // part w covers c in [192w, 192w+192); output dim d = lane (coalesced Wq)
  float acc = 0.f;
  int c0 = w*192;
  #pragma unroll 4
  for (int cc = c0; cc < c0+192; ++cc)
    acc += xs[cc]*Wq[(size_t)cc*C + h*D + lane];
  qred[w][lane] = acc;
  __syncthreads();
  if (tid < D)
    qs[tid] = (qred[0][tid]+qred[1][tid]+qred[2][tid]+qred[3][tid])*SCALE;
  __syncthreads();
  float qv = qs[lane];
  for (int c = w; c < C; c += 4){
    float wv = Wkv[(size_t)c*(2*C) + h*D + lane];
    float p = qv * wv;
    #pragma unroll
    for (int m = 1; m < 64; m <<= 1) p += __shfl_xor(p, m, 64);
    if (lane == 0) r[((size_t)b*H + h)*C + c] = p;
  }
}

// K2 (fused): per (b, chunk): scores -> online softmax -> unnormalized xbar.
// One pass over x. Partials: pm/pl [B][CH][H], pxb [B][CH][H][C].
__global__ __launch_bounds__(256)
void k_fused(const float* __restrict__ x, const float* __restrict__ r,
             float* __restrict__ pm, float* __restrict__ pl,
             float* __restrict__ pxb){
  int b = blockIdx.x, ch = blockIdx.y;
  int tid = threadIdx.x, w = tid >> 6, lane = tid & 63;

  __shared__ float xs[TILE][C];       // 24576 B token tile
  __shared__ float scr[TILE][H][20];  // 7680 B  16-lane score partials (padded)
  __shared__ float sc[TILE][16];      // tile scores
  __shared__ float wts[TILE][16];     // tile softmax weights
  __shared__ float als[16];           // per-head rescale factor

  // per-wave r rows (heads 3w..3w+2) held in registers, loaded once (coalesced)
  f4 rr4[3][3];
  {
    const float* rb = r + ((size_t)b*H + 3*w)*C + 4*lane;
    #pragma unroll
    for (int hh = 0; hh < 3; ++hh)
      #pragma unroll
      for (int jj = 0; jj < 3; ++jj)
        rr4[hh][jj] = *(const f4*)(rb + hh*C + 256*jj);
  }

  float m0 = -1e30f, l0 = 0.f;   // live in threads 0..11 only
  float xb[H][3];
  #pragma unroll
  for (int h = 0; h < H; ++h){ xb[h][0]=0.f; xb[h][1]=0.f; xb[h][2]=0.f; }

  const float* gx = x + ((size_t)b*N + (size_t)ch*NT)*C;
  f4 pf[6];
  #pragma unroll
  for (int k = 0; k < 6; ++k) pf[k] = ((const f4*)gx)[tid + 256*k];

  for (int tt = 0; tt < NTILE; ++tt){
    // stage prefetched tile, issue prefetch for next tile (hides HBM latency)
    f4* xd = (f4*)&xs[0][0];
    #pragma unroll
    for (int k = 0; k < 6; ++k) xd[tid + 256*k] = pf[k];
    if (tt + 1 < NTILE){
      const f4* gn = (const f4*)(gx + (size_t)(tt+1)*TILE*C);
      #pragma unroll
      for (int k = 0; k < 6; ++k) pf[k] = gn[tid + 256*k];
    }
    __syncthreads();                       // (1) xs ready

    // ---- scores: wave w computes heads 3w..3w+2; token halves split to
    // cut live accumulators (register pressure) 24 -> 12
    #pragma unroll
    for (int hf = 0; hf < 2; ++hf){
      float acc[4][3];
      #pragma unroll
      for (int t4 = 0; t4 < 4; ++t4){ acc[t4][0]=0.f; acc[t4][1]=0.f; acc[t4][2]=0.f; }
      #pragma unroll
      for (int t4 = 0; t4 < 4; ++t4){
        int t = hf*4 + t4;
        f4 p0 = *(const f4*)&xs[t][4*lane];
        f4 p1 = *(const f4*)&xs[t][4*lane + 256];
        f4 p2 = *(const f4*)&xs[t][4*lane + 512];
        #pragma unroll
        for (int hh = 0; hh < 3; ++hh){
          f4 r0 = rr4[hh][0], r1 = rr4[hh][1], r2 = rr4[hh][2];
          acc[t4][hh] += p0.x*r0.x + p0.y*r0.y + p0.z*r0.z + p0.w*r0.w
                       + p1.x*r1.x + p1.y*r1.y + p1.z*r1.z + p1.w*r1.w
                       + p2.x*r2.x + p2.y*r2.y + p2.z*r2.z + p2.w*r2.w;
        }
      }
      #pragma unroll
      for (int t4 = 0; t4 < 4; ++t4)
        #pragma unroll
        for (int hh = 0; hh < 3; ++hh){
          acc[t4][hh] += __shfl_xor(acc[t4][hh], 32, 64);
          acc[t4][hh] += __shfl_xor(acc[t4][hh], 16, 64);
        }
      if (lane < 16){
        #pragma unroll
        for (int t4 = 0; t4 < 4; ++t4)
          #pragma unroll
          for (int hh = 0; hh < 3; ++hh)
            scr[hf*4 + t4][3*w + hh][lane] = acc[t4][hh];
      }
    }
    __syncthreads();                       // (2) scr ready

    // ---- final reduce 16 -> 1: 96 threads, one (t,h) each
    if (tid < 96){
      int t8 = tid & 7, h12 = tid >> 3;
      float s = 0.f;
      #pragma unroll
      for (int qq = 0; qq < 4; ++qq){
        f4 v = *(const f4*)&scr[t8][h12][4*qq];
        s += v.x + v.y + v.z + v.w;
      }
      sc[t8][h12] = s;
    }
    __syncthreads();                       // (3) sc ready

    // ---- online-softmax state update (threads 0..11, one head each)
    if (tid < H){
      float tm = sc[0][tid];
      #pragma unroll
      for (int t = 1; t < TILE; ++t) tm = fmaxf(tm, sc[t][tid]);
      float mnew = fmaxf(m0, tm);
      float alpha = __expf(m0 - mnew);
      float wsum = 0.f;
      #pragma unroll
      for (int t = 0; t < TILE; ++t){
        float wv = __expf(sc[t][tid] - mnew);
        wts[t][tid] = wv;
        wsum += wv;
      }
      l0 = l0*alpha + wsum;
      m0 = mnew;
      als[tid] = alpha;
    }
    __syncthreads();                       // (4) wts/als ready

    // ---- xbar accumulate: thread owns c = {tid, tid+256, tid+512}, all heads
    f4 av0 = *(const f4*)&als[0];
    f4 av1 = *(const f4*)&als[4];
    f4 av2 = *(const f4*)&als[8];
    float alf[H] = {av0.x,av0.y,av0.z,av0.w, av1.x,av1.y,av1.z,av1.w,
                    av2.x,av2.y,av2.z,av2.w};
    #pragma unroll
    for (int h = 0; h < H; ++h){
      xb[h][0] *= alf[h]; xb[h][1] *= alf[h]; xb[h][2] *= alf[h];
    }
    #pragma unroll
    for (int t = 0; t < TILE; ++t){
      f4 w0 = *(const f4*)&wts[t][0];
      f4 w1 = *(const f4*)&wts[t][4];
      f4 w2 = *(const f4*)&wts[t][8];
      float wf[H] = {w0.x,w0.y,w0.z,w0.w, w1.x,w1.y,w1.z,w1.w,
                     w2.x,w2.y,w2.z,w2.w};
      float x0 = xs[t][tid], x1 = xs[t][tid+256], x2 = xs[t][tid+512];
      #pragma unroll
      for (int h = 0; h < H; ++h){
        xb[h][0] += wf[h]*x0;
        xb[h][1] += wf[h]*x1;
        xb[h][2] += wf[h]*x2;
      }
    }
    __syncthreads();                       // (5) xs/wts free for next tile
  }

  // write partials
  size_t pbase = ((size_t)b*CH + ch)*H;
  if (tid < H){ pm[pbase + tid] = m0; pl[pbase + tid] = l0; }
  #pragma unroll
  for (int h = 0; h < H; ++h){
    size_t o = (pbase + h)*C + tid;
    pxb[o]       = xb[h][0];
    pxb[o + 256] = xb[h][1];
    pxb[o + 512] = xb[h][2];
  }
}

// K3: merge partials -> xbar[b,h,:], then cls[b][h*64+d] = sum_c xbar * WkvV
__global__ __launch_bounds__(256)
void k_cls(const float* __restrict__ pm, const float* __restrict__ pl,
           const float* __restrict__ pxb, const float* __restrict__ Wkv,
           float* __restrict__ cls){
  int b = blockIdx.x, h = blockIdx.y, tid = threadIdx.x;
  __shared__ float xsm[C];
  float M = -1e30f;
  #pragma unroll
  for (int c = 0; c < CH; ++c) M = fmaxf(M, pm[((size_t)b*CH + c)*H + h]);
  float L = 0.f;
  float eh[CH];
  #pragma unroll
  for (int c = 0; c < CH; ++c){
    eh[c] = __expf(pm[((size_t)b*CH + c)*H + h] - M);
    L += pl[((size_t)b*CH + c)*H + h]*eh[c];
  }
  float inv = 1.f/L;
  #pragma unroll
  for (int k = 0; k < 3; ++k){
    int c = tid + 256*k;
    float acc = 0.f;
    #pragma unroll 8
    for (int q = 0; q < CH; ++q)
      acc += eh[q]*pxb[(((size_t)b*CH + q)*H + h)*C + c];
    xsm[c] = acc*inv;
  }
  __syncthreads();
  int d = tid & 63, part = tid >> 6;
  float acc = 0.f;
  int c0 = part*192;
  #pragma unroll 4
  for (int cc = c0; cc < c0 + 192; ++cc)
    acc += xsm[cc]*Wkv[(size_t)cc*(2*C) + C + h*D + d];
  __shared__ float red[4][D];
  red[part][d] = acc; __syncthreads();
  if (tid < D)
    cls[(size_t)b*C + h*D + tid] = red[0][tid]+red[1][tid]+red[2][tid]+red[3][tid];
}

// K4: out[b][j] = bp[j] + sum_i cls[b][i] * Wp[i][j]
__global__ __launch_bounds__(256)
void k_out(const float* __restrict__ cls, const float* __restrict__ Wp,
           const float* __restrict__ bp, float* __restrict__ out){
  int b = blockIdx.x, jb = blockIdx.y, tid = threadIdx.x;
  __shared__ float xs[C];
  for (int i = tid; i < C; i += 256) xs[i] = cls[(size_t)b*C + i];
  __syncthreads();
  int j = jb*256 + tid;
  float acc = bp[j];
  #pragma unroll 4
  for (int i = 0; i < C; ++i) acc += xs[i]*Wp[(size_t)i*C + j];
  out[(size_t)b*C + j] = acc;
}

extern "C" void kernel_launch(void* const* d_in, const int* in_sizes, int n_in,
                              void* d_out, int out_size, void* d_ws, size_t ws_size,
                              hipStream_t stream){
  const float* x   = (const float*)d_in[0];
  const float* Wq  = (const float*)d_in[1];
  const float* Wkv = (const float*)d_in[2];
  const float* Wp  = (const float*)d_in[3];
  const float* bp  = (const float*)d_in[4];
  float* out = (float*)d_out;
  char* ws = (char*)d_ws;
  float* r   = (float*)(ws + 0);          //  1,179,648 B
  float* pm  = (float*)(ws + 1179648);    //     49,152 B
  float* pl  = (float*)(ws + 1228800);    //     49,152 B
  float* pxb = (float*)(ws + 1277952);    // 37,748,736 B
  float* cls = (float*)(ws + 39026688);   //     98,304 B  (total 39,124,992 B)

  k_qr   <<<dim3(B,H),  dim3(256), 0, stream>>>(x, Wq, Wkv, r);
  k_fused<<<dim3(B,CH), dim3(256), 0, stream>>>(x, r, pm, pl, pxb);
  k_cls  <<<dim3(B,H),  dim3(256), 0, stream>>>(pm, pl, pxb, Wkv, cls);
  k_out  <<<dim3(B,3),  dim3(256), 0, stream>>>(cls, Wp, bp, out);
}